// Round 7
// baseline (239.222 us; speedup 1.0000x reference)
//
#include <hip/hip_runtime.h>
#include <math.h>

// z_t = a*x_t + b*z_{t-1}, z_{-1}=0 per row; a = 0.5*tanh(raw_a), b = tanh(raw_b).
// One 256-thread block (4 waves) per row of T=8192. Wave w owns 2048 contiguous
// elems as 8 sub-blocks of 256 (lane owns 4 contiguous floats per sub-block ->
// every dwordx4 is unit-stride). 8 independent loads in flight per thread.
// One barrier; all threads redundantly fold the 4-wide wave-carry (no wave0 phase).
// All decay powers via repeated squaring — no powf.

typedef float f32x4 __attribute__((ext_vector_type(4)));

#define T_LEN 8192
#define NSUB  8

__global__ __launch_bounds__(256) void lincell_scan(
    const float* __restrict__ X,
    const float* __restrict__ pa,
    const float* __restrict__ pb,
    float* __restrict__ Z,
    int nrows)
{
    __shared__ float wsum[4];     // per-wave segment totals (2048 elems each)

    const int row  = blockIdx.x;
    const int tid  = threadIdx.x;
    const int wave = tid >> 6;    // 0..3
    const int lane = tid & 63;
    if (row >= nrows) return;

    const float a  = 0.5f * tanhf(pa[0]);
    const float b  = tanhf(pb[0]);
    const float b2 = b * b;
    const float b3 = b2 * b;
    const float b4 = b2 * b2;     // lane-segment decay m (>= 0)

    // repeated-squaring chain
    const float m1  = b4;
    const float m2  = m1  * m1;
    const float m4  = m2  * m2;
    const float m8  = m4  * m4;
    const float m16 = m8  * m8;
    const float m32 = m16 * m16;
    const float b256  = m32 * m32;        // sub-block decay  b^256
    const float b2048 = b256 * b256 * b256 * b256 * b256 * b256 * b256 * b256; // wave decay
    const float mstep[6] = { m1, m2, m4, m8, m16, m32 };

    // b4^lane via binary decomposition (no powf)
    float b4lane = 1.0f;
    b4lane *= (lane & 1)  ? m1  : 1.0f;
    b4lane *= (lane & 2)  ? m2  : 1.0f;
    b4lane *= (lane & 4)  ? m4  : 1.0f;
    b4lane *= (lane & 8)  ? m8  : 1.0f;
    b4lane *= (lane & 16) ? m16 : 1.0f;
    b4lane *= (lane & 32) ? m32 : 1.0f;

    const f32x4* xrow = (const f32x4*)(X + (size_t)row * T_LEN);
    f32x4*       zrow = (f32x4*)(Z + (size_t)row * T_LEN);

    // ---- load: 8 independent unit-stride dwordx4 per thread ----
    const int vbase = wave * 512 + lane;   // wave covers vec slots [wave*512, +512)
    f32x4 v[NSUB];
#pragma unroll
    for (int j = 0; j < NSUB; ++j) v[j] = xrow[vbase + j * 64];

    // ---- in-lane serial scans, 8 independent 4-chains (ILP) ----
    float y0[NSUB], y1[NSUB], y2[NSUB], y3[NSUB], s[NSUB];
#pragma unroll
    for (int j = 0; j < NSUB; ++j) {
        y0[j] = a * v[j].x;
        y1[j] = fmaf(b, y0[j], a * v[j].y);
        y2[j] = fmaf(b, y1[j], a * v[j].z);
        y3[j] = fmaf(b, y2[j], a * v[j].w);
        s[j]  = y3[j];
    }

    // ---- cross-lane affine scans: 8 interleaved chains (shfl latency hidden) ----
#pragma unroll
    for (int k = 0; k < 6; ++k) {
#pragma unroll
        for (int j = 0; j < NSUB; ++j) {
            float t = __shfl_up(s[j], (unsigned)(1 << k), 64);
            t = (lane >= (1 << k)) ? t : 0.0f;
            s[j] = fmaf(mstep[k], t, s[j]);
        }
    }
    float excl[NSUB], tot[NSUB];
#pragma unroll
    for (int j = 0; j < NSUB; ++j) {
        float e = __shfl_up(s[j], 1u, 64);
        excl[j] = (lane >= 1) ? e : 0.0f;
        tot[j]  = __shfl(s[j], 63, 64);
    }

    // wave total over its 2048 elems (serial fold, 8 fma)
    float Wt = tot[0];
#pragma unroll
    for (int j = 1; j < NSUB; ++j) Wt = fmaf(b256, Wt, tot[j]);
    if (lane == 0) wsum[wave] = Wt;
    __syncthreads();

    // ---- every thread folds its wave's carry (<= 3 fma, wave-uniform) ----
    float carry = 0.0f;
    if (wave > 0) carry = wsum[0];
    if (wave > 1) carry = fmaf(b2048, carry, wsum[1]);
    if (wave > 2) carry = fmaf(b2048, carry, wsum[2]);

    // ---- chain sub-blocks, apply, store ----
    float cj = carry;
#pragma unroll
    for (int j = 0; j < NSUB; ++j) {
        const float pre = fmaf(b4lane, cj, excl[j]);   // z before this lane's elems
        f32x4 o;
        o.x = fmaf(b,  pre, y0[j]);
        o.y = fmaf(b2, pre, y1[j]);
        o.z = fmaf(b3, pre, y2[j]);
        o.w = fmaf(b4, pre, y3[j]);
        __builtin_nontemporal_store(o, &zrow[vbase + j * 64]);
        cj = fmaf(b256, cj, tot[j]);
    }
}

extern "C" void kernel_launch(void* const* d_in, const int* in_sizes, int n_in,
                              void* d_out, int out_size, void* d_ws, size_t ws_size,
                              hipStream_t stream) {
    const float* X  = (const float*)d_in[0];
    const float* pa = (const float*)d_in[1];
    const float* pb = (const float*)d_in[2];
    float* Z = (float*)d_out;

    const int nrows = in_sizes[0] / T_LEN;   // 4096
    lincell_scan<<<nrows, 256, 0, stream>>>(X, pa, pb, Z, nrows);
}

// Round 8
// 233.470 us; speedup vs baseline: 1.0246x; 1.0246x over previous
//
#include <hip/hip_runtime.h>
#include <math.h>

// z_t = a*x_t + b*z_{t-1}, z_{-1}=0 per row; a = 0.5*tanh(raw_a), b = tanh(raw_b).
// One 512-thread block (8 waves) per row of T=8192. Wave w owns 1024 contiguous
// elems (4 KB) staged into LDS via 4 back-to-back global_load_lds_dwordx4 —
// async, vmcnt-tracked, zero VGPR results -> guaranteed 4 KB/wave in flight.
// Staging is wave-private (own vmcnt(0) wait, no barrier). Scan math identical
// to the verified R7 kernel, NSUB=4. One __syncthreads for the 8-wide carry.

typedef float f32x4 __attribute__((ext_vector_type(4)));

#define T_LEN 8192
#define NSUB  4            // sub-blocks of 256 elems per wave
#define WPB   8            // waves per block
#define WELEM 1024         // elems per wave

__device__ __forceinline__ void gload_lds16(const float* g, float* l) {
    __builtin_amdgcn_global_load_lds(
        (const __attribute__((address_space(1))) void*)g,
        (__attribute__((address_space(3))) void*)l, 16, 0, 0);
}

__global__ __launch_bounds__(512) void lincell_scan(
    const float* __restrict__ X,
    const float* __restrict__ pa,
    const float* __restrict__ pb,
    float* __restrict__ Z,
    int nrows)
{
    __shared__ float lds[T_LEN];   // 32 KB: whole row staged, [wave][1024]
    __shared__ float wsum[WPB];

    const int row  = blockIdx.x;
    const int tid  = threadIdx.x;
    const int wave = tid >> 6;     // 0..7
    const int lane = tid & 63;
    if (row >= nrows) return;

    const float* xrow = X + (size_t)row * T_LEN;
    float*       zrow = Z + (size_t)row * T_LEN;

    // ---- async stage: 4 x 1KB per wave, back-to-back, wave-private region ----
    {
        const float* g = xrow + wave * WELEM + lane * 4;
        float*       l = lds + wave * WELEM;     // wave-uniform base (HW adds lane*16)
#pragma unroll
        for (int j = 0; j < NSUB; ++j)
            gload_lds16(g + j * 256, l + j * 256);
    }

    // ---- scalar setup overlaps the staging latency ----
    const float a  = 0.5f * tanhf(pa[0]);
    const float b  = tanhf(pb[0]);
    const float b2 = b * b;
    const float b3 = b2 * b;
    const float b4 = b2 * b2;      // lane-segment decay m (>= 0)

    const float m1  = b4;
    const float m2  = m1  * m1;
    const float m4  = m2  * m2;
    const float m8  = m4  * m4;
    const float m16 = m8  * m8;
    const float m32 = m16 * m16;
    const float b256  = m32 * m32;            // sub-block decay  b^256
    const float b1024 = b256 * b256 * b256 * b256;  // wave decay b^1024
    const float mstep[6] = { m1, m2, m4, m8, m16, m32 };

    float b4lane = 1.0f;           // b4^lane via binary decomposition
    b4lane *= (lane & 1)  ? m1  : 1.0f;
    b4lane *= (lane & 2)  ? m2  : 1.0f;
    b4lane *= (lane & 4)  ? m4  : 1.0f;
    b4lane *= (lane & 8)  ? m8  : 1.0f;
    b4lane *= (lane & 16) ? m16 : 1.0f;
    b4lane *= (lane & 32) ? m32 : 1.0f;

    // wait for this wave's own staged data (no barrier needed)
    asm volatile("s_waitcnt vmcnt(0)" ::: "memory");

    // ---- read fragments from LDS ----
    const f32x4* lf4 = (const f32x4*)lds;
    f32x4 v[NSUB];
#pragma unroll
    for (int j = 0; j < NSUB; ++j)
        v[j] = lf4[wave * 256 + j * 64 + lane];

    // ---- in-lane serial scans, 4 independent chains ----
    float y0[NSUB], y1[NSUB], y2[NSUB], y3[NSUB], s[NSUB];
#pragma unroll
    for (int j = 0; j < NSUB; ++j) {
        y0[j] = a * v[j].x;
        y1[j] = fmaf(b, y0[j], a * v[j].y);
        y2[j] = fmaf(b, y1[j], a * v[j].z);
        y3[j] = fmaf(b, y2[j], a * v[j].w);
        s[j]  = y3[j];
    }

    // ---- cross-lane affine scans: s_i += m^(2^k) * s_{i-2^k} ----
#pragma unroll
    for (int k = 0; k < 6; ++k) {
#pragma unroll
        for (int j = 0; j < NSUB; ++j) {
            float t = __shfl_up(s[j], (unsigned)(1 << k), 64);
            t = (lane >= (1 << k)) ? t : 0.0f;
            s[j] = fmaf(mstep[k], t, s[j]);
        }
    }
    float excl[NSUB], tot[NSUB];
#pragma unroll
    for (int j = 0; j < NSUB; ++j) {
        float e = __shfl_up(s[j], 1u, 64);
        excl[j] = (lane >= 1) ? e : 0.0f;
        tot[j]  = __shfl(s[j], 63, 64);
    }

    // wave total over its 1024 elems
    float Wt = tot[0];
#pragma unroll
    for (int j = 1; j < NSUB; ++j) Wt = fmaf(b256, Wt, tot[j]);
    if (lane == 0) wsum[wave] = Wt;
    __syncthreads();

    // ---- every thread folds its wave's carry (<=7 predicated fma) ----
    float carry = 0.0f;
#pragma unroll
    for (int k = 0; k < WPB - 1; ++k)
        carry = (wave > k) ? fmaf(b1024, carry, wsum[k]) : carry;

    // ---- chain sub-blocks, apply, store (unit-stride dwordx4) ----
    f32x4* zf4 = (f32x4*)zrow;
    float cj = carry;
#pragma unroll
    for (int j = 0; j < NSUB; ++j) {
        const float pre = fmaf(b4lane, cj, excl[j]);   // z before this lane's elems
        f32x4 o;
        o.x = fmaf(b,  pre, y0[j]);
        o.y = fmaf(b2, pre, y1[j]);
        o.z = fmaf(b3, pre, y2[j]);
        o.w = fmaf(b4, pre, y3[j]);
        zf4[wave * 256 + j * 64 + lane] = o;
        cj = fmaf(b256, cj, tot[j]);
    }
}

extern "C" void kernel_launch(void* const* d_in, const int* in_sizes, int n_in,
                              void* d_out, int out_size, void* d_ws, size_t ws_size,
                              hipStream_t stream) {
    const float* X  = (const float*)d_in[0];
    const float* pa = (const float*)d_in[1];
    const float* pb = (const float*)d_in[2];
    float* Z = (float*)d_out;

    const int nrows = in_sizes[0] / T_LEN;   // 4096
    lincell_scan<<<nrows, 512, 0, stream>>>(X, pa, pb, Z, nrows);
}